// Round 13
// baseline (577.111 us; speedup 1.0000x reference)
//
#include <hip/hip_runtime.h>

#define NN 100000
#define NE 1600000
#define DIM 128
#define NT 13            // src tiles: src>>13 -> 8192 rows = 2 MB bf16 per tile (fits 4 MB L2)
#define SH 13
#define LEN (NN * NT)    // buckets, rowgroup-major: idx = (dst>>3)*104 + tt*8 + (dst&7)
#define NB_SCAN ((LEN + 1023) / 1024)
#define FST 140          // smF row stride (dwords): 16B-aligned, 2-way banks only
#define CHA 2048         // edges per binning block

typedef __attribute__((ext_vector_type(8))) short short8;
typedef __attribute__((ext_vector_type(4))) float f4;
typedef __attribute__((ext_vector_type(4))) unsigned u4;

__device__ __forceinline__ unsigned short f2bf(float f){
  unsigned x = __float_as_uint(f);
  x += 0x7fffu + ((x >> 16) & 1u);
  return (unsigned short)(x >> 16);
}
__device__ __forceinline__ unsigned pack2(float lo, float hi){
  return ((unsigned)f2bf(hi) << 16) | (unsigned)f2bf(lo);
}
__device__ __forceinline__ float blo(unsigned u){ return __uint_as_float(u << 16); }
__device__ __forceinline__ float bhi(unsigned u){ return __uint_as_float(u & 0xffff0000u); }
__device__ __forceinline__ short8 cvt8(f4 a, f4 b){
  short8 r;
  #pragma unroll
  for (int j = 0; j < 4; ++j){ r[j] = (short)f2bf(a[j]); r[j+4] = (short)f2bf(b[j]); }
  return r;
}

// ---------------- fallback sentinel ----------------
__global__ void k_sentinel(float* __restrict__ out, int n){
  int i = blockIdx.x * blockDim.x + threadIdx.x;
  if (i < n) out[i] = 12345.0f;
}

// ---------------- x fp32 -> bf16x2 ----------------
__global__ void k_cvt(const float* __restrict__ x, unsigned* __restrict__ xb){
  int i = blockIdx.x * blockDim.x + threadIdx.x;   // i < NN*16
  if (i >= NN * 16) return;
  f4 a = ((const f4*)x)[2 * i];
  f4 b = ((const f4*)x)[2 * i + 1];
  u4 o;
  o[0] = pack2(a[0], a[1]); o[1] = pack2(a[2], a[3]);
  o[2] = pack2(b[0], b[1]); o[3] = pack2(b[2], b[3]);
  ((u4*)xb)[i] = o;
}

// ---------------- histogram (rowgroup-major buckets) ----------------
__global__ void k_hist(const int* __restrict__ src, const int* __restrict__ dst,
                       int* __restrict__ cnt){
  int i = blockIdx.x * blockDim.x + threadIdx.x;
  if (i < NE){
    int s = src[i], d = dst[i];
    atomicAdd(&cnt[(d >> 3) * 104 + (s >> SH) * 8 + (d & 7)], 1);
  }
}

__global__ void k_deg(const int* __restrict__ cnt, int* __restrict__ deg){
  int i = blockIdx.x * blockDim.x + threadIdx.x;
  if (i < NN){
    int g = i >> 3, r = i & 7;
    int s = 0;
    #pragma unroll
    for (int tt = 0; tt < NT; ++tt) s += cnt[g * 104 + tt * 8 + r];
    deg[i] = s;
  }
}

// ---------------- per-tile totals (for binned regions) ----------------
__global__ __launch_bounds__(256)
void k_cntA(const int* __restrict__ src, int* __restrict__ gcnt){
  __shared__ int shw[4][16];
  int t = threadIdx.x, lane = t & 63, wv = t >> 6;
  int base0 = blockIdx.x * CHA + wv * (CHA / 4);
  int c[13];
  #pragma unroll
  for (int i = 0; i < 13; ++i) c[i] = 0;
  for (int r = 0; r < CHA / 4 / 64; ++r){
    int idx = base0 + r * 64 + lane;
    int tt = 31;
    if (idx < NE) tt = src[idx] >> SH;
    #pragma unroll
    for (int ti = 0; ti < 13; ++ti)
      c[ti] += __popcll(__ballot(tt == ti));
  }
  #pragma unroll
  for (int ti = 0; ti < 13; ++ti)
    if (lane == ti) shw[wv][ti] = c[ti];
  __syncthreads();
  if (t < 13)
    atomicAdd(&gcnt[t], shw[0][t] + shw[1][t] + shw[2][t] + shw[3][t]);
}

__global__ void k_tscan(const int* __restrict__ gcnt, int* __restrict__ tbase,
                        int* __restrict__ tcur){
  if (threadIdx.x == 0){
    int run = 0;
    for (int i = 0; i < 13; ++i){ tbase[i] = run; tcur[i] = run; run += gcnt[i]; }
    tbase[13] = run;
  }
}

__global__ void k_bsum(const int* __restrict__ cnt, int* __restrict__ bsum, int len){
  __shared__ int sh[256];
  int t = threadIdx.x, b = blockIdx.x;
  int base = b * 1024 + t * 4;
  int s = 0;
  #pragma unroll
  for (int j = 0; j < 4; ++j){ int i = base + j; if (i < len) s += cnt[i]; }
  sh[t] = s; __syncthreads();
  for (int off = 128; off > 0; off >>= 1){
    if (t < off) sh[t] += sh[t + off];
    __syncthreads();
  }
  if (t == 0) bsum[b] = sh[0];
}

__global__ void k_scanp(const int* __restrict__ bsum, int* __restrict__ boff, int nb){
  __shared__ int sh[256];
  int t = threadIdx.x;
  int chunk = (nb + 255) / 256;
  int s = 0;
  for (int j = 0; j < chunk; ++j){ int i = t * chunk + j; if (i < nb) s += bsum[i]; }
  sh[t] = s; __syncthreads();
  int tin = s;
  for (int off = 1; off < 256; off <<= 1){
    int u = (t >= off) ? sh[t - off] : 0;
    __syncthreads();
    sh[t] += u;
    __syncthreads();
  }
  int run = sh[t] - tin;
  for (int j = 0; j < chunk; ++j){
    int i = t * chunk + j;
    if (i < nb){ boff[i] = run; run += bsum[i]; }
  }
}

__global__ void k_scanf(const int* __restrict__ cnt, const int* __restrict__ boff,
                        int* __restrict__ rp, int* __restrict__ pos, int len){
  __shared__ int sh[256];
  int t = threadIdx.x, b = blockIdx.x;
  int base = b * 1024 + t * 4;
  int c[4]; int s = 0;
  #pragma unroll
  for (int j = 0; j < 4; ++j){ int i = base + j; c[j] = (i < len) ? cnt[i] : 0; s += c[j]; }
  sh[t] = s; __syncthreads();
  int tin = s;
  for (int off = 1; off < 256; off <<= 1){
    int u = (t >= off) ? sh[t - off] : 0;
    __syncthreads();
    sh[t] += u;
    __syncthreads();
  }
  int run = boff[b] + sh[t] - tin;
  #pragma unroll
  for (int j = 0; j < 4; ++j){
    int i = base + j;
    if (i < len){
      rp[i] = run; pos[i] = run; run += c[j];
      if (i == len - 1) rp[len] = run;
    }
  }
}

// ---------------- binning: write edges to tile regions (coalesced chunks) ----
// entry = (dst<<13) | (src&8191)
__global__ __launch_bounds__(256)
void k_binw(const int* __restrict__ src, const int* __restrict__ dst,
            int* __restrict__ tcur, unsigned* __restrict__ binned){
  __shared__ int shw[4][16];
  int t = threadIdx.x, lane = t & 63, wv = t >> 6;
  int base0 = blockIdx.x * CHA + wv * (CHA / 4);
  unsigned long long lt = (1ull << lane) - 1ull;
  int c[13];
  #pragma unroll
  for (int i = 0; i < 13; ++i) c[i] = 0;
  for (int r = 0; r < CHA / 4 / 64; ++r){
    int idx = base0 + r * 64 + lane;
    int tt = 31;
    if (idx < NE) tt = src[idx] >> SH;
    #pragma unroll
    for (int ti = 0; ti < 13; ++ti)
      c[ti] += __popcll(__ballot(tt == ti));
  }
  #pragma unroll
  for (int ti = 0; ti < 13; ++ti)
    if (lane == ti) shw[wv][ti] = c[ti];
  __syncthreads();
  if (t < 13){
    int s = shw[0][t] + shw[1][t] + shw[2][t] + shw[3][t];
    int run = atomicAdd(&tcur[t], s);
    #pragma unroll
    for (int w = 0; w < 4; ++w){ int tmp = shw[w][t]; shw[w][t] = run; run += tmp; }
  }
  __syncthreads();
  int wb[13];
  #pragma unroll
  for (int ti = 0; ti < 13; ++ti) wb[ti] = shw[wv][ti];
  for (int r = 0; r < CHA / 4 / 64; ++r){
    int idx = base0 + r * 64 + lane;
    int tt = 31, s = 0, d = 0;
    if (idx < NE){ s = src[idx]; d = dst[idx]; tt = s >> SH; }
    unsigned entry = ((unsigned)d << 13) | (unsigned)(s & 8191);
    #pragma unroll
    for (int ti = 0; ti < 13; ++ti){
      unsigned long long m = __ballot(tt == ti);
      if (tt == ti) binned[wb[ti] + __popcll(m & lt)] = entry;
      wb[ti] += __popcll(m);
    }
  }
}

// ---------------- scatter to ss16 ----------------
__global__ void k_binB(const unsigned* __restrict__ binned, const int* __restrict__ tbase,
                       int* __restrict__ pos, unsigned short* __restrict__ ss16){
  __shared__ int tb[14];
  int t = threadIdx.x;
  if (t < 14) tb[t] = tbase[t];
  __syncthreads();
  for (int i = blockIdx.x * 256 + t; i < NE; i += 1024 * 256){
    int tt = 0;
    #pragma unroll
    for (int k = 1; k < 13; ++k) tt += (i >= tb[k]);
    unsigned e = binned[i];
    int d = (int)(e >> 13);
    int p = atomicAdd(&pos[(d >> 3) * 104 + tt * 8 + (d & 7)], 1);
    ss16[p] = (unsigned short)((e & 8191u) | ((unsigned)(d & 7) << 13));
  }
}

// ---------------- W packing ----------------
template<int NB16>
__global__ void k_pack(const float* __restrict__ Wl,
                       const float* __restrict__ Wr,
                       unsigned short* __restrict__ Bp){
  constexpr int DOUT = NB16 * 16;
  int idx = blockIdx.x * blockDim.x + threadIdx.x;
  if (idx >= 8 * NB16 * 64) return;
  int lane = idx & 63;
  int nb = (idx >> 6) % NB16;
  int ks = idx / (64 * NB16);
  int n = nb * 16 + (lane & 15);
  int k0 = ks * 32 + (lane >> 4) * 8;
  short8 v;
  #pragma unroll
  for (int j = 0; j < 8; ++j){
    int k = k0 + j;
    float w = (k < 128) ? Wl[k * DOUT + n] : Wr[(k - 128) * DOUT + n];
    v[j] = (short)f2bf(w);
  }
  ((short8*)Bp)[idx] = v;
}

// ---------------- fused tiled mean-aggregate + dual-GEMM (+BN+ReLU) ----------
// Rowgroup-major ss16: the wave's 128-edge worklist is ONE contiguous range,
// ordered (tile,row). Tags loaded 8-at-a-time via aligned u4 (scalar path);
// tile tracked by rare wave-uniform advances over prefetched bounds.
template<int NB16, bool DO_BN>
__global__ __launch_bounds__(256)
void k_fused(const unsigned* __restrict__ Xb,
             const int* __restrict__ rp2, const unsigned short* __restrict__ ss16,
             const int* __restrict__ deg,
             const unsigned short* __restrict__ Bp,
             const float* __restrict__ bias,
             const float* __restrict__ bg, const float* __restrict__ bb,
             const float* __restrict__ bm, const float* __restrict__ bv,
             unsigned short* __restrict__ OutB, float* __restrict__ OutF){
  constexpr int DOUT = NB16 * 16;
  constexpr int NBW = NB16 / 4;
  __shared__ float smF[32][FST];
  const int t = threadIdx.x;
  const int lane = t & 63;
  const int wv = t >> 6;
  const int m0 = blockIdx.x * 32;
  const int row0 = m0 + wv * 8;
  const int g = row0 >> 3;

  for (int i = t; i < 32 * FST; i += 256) (&smF[0][0])[i] = 0.f;
  __syncthreads();

  float* const base = &smF[wv * 8][0];

  // bounds: rp2[g*104 + k*8], k=0..13 (k=13 -> next rowgroup start = range end)
  int bAll = (lane < 14) ? rp2[g * 104 + lane * 8] : 0;

  int tt = 0;
  int e        = __builtin_amdgcn_readfirstlane(__shfl(bAll, 0));
  const int end= __builtin_amdgcn_readfirstlane(__shfl(bAll, 13));
  int nb       = __builtin_amdgcn_readfirstlane(__shfl(bAll, 1));

  float cx = 0.f, cy = 0.f;
  int cur = 0;

  #define ADV(ee) { while ((ee) >= nb){ ++tt; nb = __builtin_amdgcn_readfirstlane(__shfl(bAll, tt + 1)); } }
  #define ONE(tg) { \
    int _row = (tg) >> 13; \
    unsigned _u = Xb[(size_t)(((unsigned)tt << SH) | ((unsigned)(tg) & 8191u)) * 64 + lane]; \
    if (_row != cur){ float* _p = base + cur * FST + 2 * lane; _p[0] += cx; _p[1] += cy; cx = 0.f; cy = 0.f; cur = _row; } \
    cx += blo(_u); cy += bhi(_u); }

  // head peel to 16B alignment (once per wave)
  while (e < end && (e & 7)){
    ADV(e);
    int tg = __builtin_amdgcn_readfirstlane((int)ss16[e]);
    ONE(tg);
    ++e;
  }
  // body: 8 tags per aligned 16B load; compute -> gather -> consume
  while (e + 8 <= end){
    u4 q = *(const u4*)(ss16 + e);
    unsigned d0 = __builtin_amdgcn_readfirstlane(q[0]);
    unsigned d1 = __builtin_amdgcn_readfirstlane(q[1]);
    unsigned d2 = __builtin_amdgcn_readfirstlane(q[2]);
    unsigned d3 = __builtin_amdgcn_readfirstlane(q[3]);
    int tg[8] = { (int)(d0 & 0xffffu), (int)(d0 >> 16), (int)(d1 & 0xffffu), (int)(d1 >> 16),
                  (int)(d2 & 0xffffu), (int)(d2 >> 16), (int)(d3 & 0xffffu), (int)(d3 >> 16) };
    unsigned sidx[8]; int row[8];
    #pragma unroll
    for (int i = 0; i < 8; ++i){
      ADV(e + i);
      sidx[i] = ((unsigned)tt << SH) | ((unsigned)tg[i] & 8191u);
      row[i] = tg[i] >> 13;
    }
    unsigned u[8];
    #pragma unroll
    for (int i = 0; i < 8; ++i) u[i] = Xb[(size_t)sidx[i] * 64 + lane];
    #pragma unroll
    for (int i = 0; i < 8; ++i){
      if (row[i] != cur){ float* _p = base + cur * FST + 2 * lane; _p[0] += cx; _p[1] += cy; cx = 0.f; cy = 0.f; cur = row[i]; }
      cx += blo(u[i]); cy += bhi(u[i]);
    }
    e += 8;
  }
  // tail peel
  while (e < end){
    ADV(e);
    int tg = __builtin_amdgcn_readfirstlane((int)ss16[e]);
    ONE(tg);
    ++e;
  }
  { float* p = base + cur * FST + 2 * lane; p[0] += cx; p[1] += cy; }
  #undef ONE
  #undef ADV
  __syncthreads();

  // normalize
  {
    int row = t >> 3;
    int d = deg[m0 + row];
    float inv = (d > 0) ? 1.f / (float)d : 0.f;
    float* pr = &smF[row][(t & 7) * 16];
    #pragma unroll
    for (int i = 0; i < 16; ++i) pr[i] *= inv;
  }
  __syncthreads();

  // ---- phase 2: dual GEMM ----
  const int q2 = lane >> 4, lr = lane & 15;
  const short8* pb = (const short8*)Bp + lane;
  f4 acc[2][NBW];
  #pragma unroll
  for (int gg = 0; gg < 2; ++gg)
    #pragma unroll
    for (int j = 0; j < NBW; ++j)
      acc[gg][j] = (f4){0.f, 0.f, 0.f, 0.f};

  #pragma unroll
  for (int ks = 0; ks < 4; ++ks){
    const float* r0 = &smF[lr][ks * 32 + q2 * 8];
    const float* r1 = &smF[lr + 16][ks * 32 + q2 * 8];
    short8 a0 = cvt8(*(const f4*)r0, *(const f4*)(r0 + 4));
    short8 a1 = cvt8(*(const f4*)r1, *(const f4*)(r1 + 4));
    #pragma unroll
    for (int j = 0; j < NBW; ++j){
      int nb2 = wv * NBW + j;
      short8 b = pb[(ks * NB16 + nb2) * 64];
      acc[0][j] = __builtin_amdgcn_mfma_f32_16x16x32_bf16(a0, b, acc[0][j], 0, 0, 0);
      acc[1][j] = __builtin_amdgcn_mfma_f32_16x16x32_bf16(a1, b, acc[1][j], 0, 0, 0);
    }
  }
  #pragma unroll
  for (int ks = 0; ks < 4; ++ks){
    short8 a0 = *(const short8*)(Xb + (size_t)(m0 + lr) * 64 + q2*4 + ks*16);
    short8 a1 = *(const short8*)(Xb + (size_t)(m0 + lr + 16) * 64 + q2*4 + ks*16);
    #pragma unroll
    for (int j = 0; j < NBW; ++j){
      int nb2 = wv * NBW + j;
      short8 b = pb[((4 + ks) * NB16 + nb2) * 64];
      acc[0][j] = __builtin_amdgcn_mfma_f32_16x16x32_bf16(a0, b, acc[0][j], 0, 0, 0);
      acc[1][j] = __builtin_amdgcn_mfma_f32_16x16x32_bf16(a1, b, acc[1][j], 0, 0, 0);
    }
  }

  // ---- epilogue ----
  #pragma unroll
  for (int j = 0; j < NBW; ++j){
    int col = (wv * NBW + j) * 16 + lr;
    float S = 1.f, T;
    if constexpr (DO_BN){
      float s = bg[col] * rsqrtf(bv[col] + 1e-5f);
      S = s;
      T = (bias[col] - bm[col]) * s + bb[col];
    } else {
      T = bias[col];
    }
    #pragma unroll
    for (int r = 0; r < 4; ++r){
      int row = m0 + q2 * 4 + r;
      float y0 = acc[0][j][r] * S + T;
      float y1 = acc[1][j][r] * S + T;
      if constexpr (DO_BN){
        y0 = y0 > 0.f ? y0 : 0.f;
        y1 = y1 > 0.f ? y1 : 0.f;
        OutB[(size_t)row * DOUT + col] = f2bf(y0);
        OutB[(size_t)(row + 16) * DOUT + col] = f2bf(y1);
      } else {
        OutF[(size_t)row * DOUT + col] = y0;
        OutF[(size_t)(row + 16) * DOUT + col] = y1;
      }
    }
  }
}

extern "C" void kernel_launch(void* const* d_in, const int* in_sizes, int n_in,
                              void* d_out, int out_size, void* d_ws, size_t ws_size,
                              hipStream_t stream){
  const float* x = (const float*)d_in[0];
  const int* ei = (const int*)d_in[1];
  const float* Wl0 = (const float*)d_in[2];
  const float* Wr0 = (const float*)d_in[3];
  const float* bl0 = (const float*)d_in[4];
  const float* Wl1 = (const float*)d_in[5];
  const float* Wr1 = (const float*)d_in[6];
  const float* bl1 = (const float*)d_in[7];
  const float* Wl2 = (const float*)d_in[8];
  const float* Wr2 = (const float*)d_in[9];
  const float* bl2 = (const float*)d_in[10];
  const float* g0 = (const float*)d_in[11];
  const float* b0 = (const float*)d_in[12];
  const float* bm0 = (const float*)d_in[13];
  const float* bv0 = (const float*)d_in[14];
  const float* g1 = (const float*)d_in[15];
  const float* b1 = (const float*)d_in[16];
  const float* bm1 = (const float*)d_in[17];
  const float* bv1 = (const float*)d_in[18];

  const size_t REQUIRED = 51600000;
  if (ws_size < REQUIRED){
    k_sentinel<<<(out_size + 255) / 256, 256, 0, stream>>>((float*)d_out, out_size);
    return;
  }

  char* w = (char*)d_ws;
  size_t off = 0;
  auto alloc = [&](size_t bytes) -> char* {
    char* p = w + off; off = (off + bytes + 255) & ~(size_t)255; return p;
  };
  int* rp2 = (int*)alloc((size_t)(LEN + 1) * 4);
  unsigned short* ss16 = (unsigned short*)alloc((size_t)NE * 2);
  unsigned* binned = (unsigned*)alloc((size_t)NE * 4);
  unsigned short* bp0 = (unsigned short*)alloc(8 * 8 * 64 * 8 * 2);
  unsigned short* bp1 = (unsigned short*)alloc(8 * 8 * 64 * 8 * 2);
  unsigned short* bp2 = (unsigned short*)alloc(8 * 4 * 64 * 8 * 2);
  unsigned* xb = (unsigned*)alloc((size_t)NN * 64 * 4);   // bf16x2 x; reused as h2
  unsigned short* h2 = (unsigned short*)xb;
  int* cnt2 = (int*)alloc((size_t)LEN * 4);
  int* pos2 = (int*)alloc((size_t)LEN * 4);
  int* deg  = (int*)alloc((size_t)NN * 4);
  int* bsum = (int*)alloc(NB_SCAN * 4);
  int* boff = (int*)alloc(NB_SCAN * 4);
  int* gcnt = (int*)alloc(256);
  int* tbase = (int*)alloc(256);
  int* tcur = (int*)alloc(256);
  unsigned short* h1 = (unsigned short*)d_out;            // 25.6 MB, exactly d_out

  const int* srcI = ei;
  const int* dstI = ei + NE;

  hipMemsetAsync(cnt2, 0, (size_t)LEN * 4, stream);
  hipMemsetAsync(gcnt, 0, 256, stream);
  k_cvt<<<(NN * 16 + 255) / 256, 256, 0, stream>>>(x, xb);
  k_hist<<<(NE + 255) / 256, 256, 0, stream>>>(srcI, dstI, cnt2);
  k_deg<<<(NN + 255) / 256, 256, 0, stream>>>(cnt2, deg);
  k_bsum<<<NB_SCAN, 256, 0, stream>>>(cnt2, bsum, LEN);
  k_scanp<<<1, 256, 0, stream>>>(bsum, boff, NB_SCAN);
  k_scanf<<<NB_SCAN, 256, 0, stream>>>(cnt2, boff, rp2, pos2, LEN);
  k_cntA<<<(NE + CHA - 1) / CHA, 256, 0, stream>>>(srcI, gcnt);
  k_tscan<<<1, 64, 0, stream>>>(gcnt, tbase, tcur);
  k_binw<<<(NE + CHA - 1) / CHA, 256, 0, stream>>>(srcI, dstI, tcur, binned);
  k_binB<<<1024, 256, 0, stream>>>(binned, tbase, pos2, ss16);
  k_pack<8><<<16, 256, 0, stream>>>(Wl0, Wr0, bp0);
  k_pack<8><<<16, 256, 0, stream>>>(Wl1, Wr1, bp1);
  k_pack<4><<<8, 256, 0, stream>>>(Wl2, Wr2, bp2);

  k_fused<8, true ><<<3125, 256, 0, stream>>>(xb, rp2, ss16, deg, bp0,
      bl0, g0, b0, bm0, bv0, h1, nullptr);
  k_fused<8, true ><<<3125, 256, 0, stream>>>((const unsigned*)h1, rp2, ss16, deg, bp1,
      bl1, g1, b1, bm1, bv1, h2, nullptr);
  k_fused<4, false><<<3125, 256, 0, stream>>>((const unsigned*)h2, rp2, ss16, deg, bp2,
      bl2, nullptr, nullptr, nullptr, nullptr, nullptr, (float*)d_out);
}

// Round 14
// 505.471 us; speedup vs baseline: 1.1417x; 1.1417x over previous
//
#include <hip/hip_runtime.h>

#define NN 100000
#define NE 1600000
#define DIM 128
#define NT 13            // src tiles: src>>13 -> 8192 rows = 2 MB bf16 per tile (fits 4 MB L2)
#define SH 13
#define LEN (NN * NT)    // buckets, rowgroup-major: idx = (dst>>3)*104 + tt*8 + (dst&7)
#define NB_SCAN ((LEN + 1023) / 1024)
#define FST 140          // smF row stride (dwords): 16B-aligned, 2-way banks only
#define NGRP 12500       // rowgroups (NN/8)
#define PW 8             // dst-window passes in k_scat
#define GW ((NGRP + PW - 1) / PW)

typedef __attribute__((ext_vector_type(8))) short short8;
typedef __attribute__((ext_vector_type(4))) float f4;
typedef __attribute__((ext_vector_type(4))) unsigned u4;

__device__ __forceinline__ unsigned short f2bf(float f){
  unsigned x = __float_as_uint(f);
  x += 0x7fffu + ((x >> 16) & 1u);
  return (unsigned short)(x >> 16);
}
__device__ __forceinline__ unsigned pack2(float lo, float hi){
  return ((unsigned)f2bf(hi) << 16) | (unsigned)f2bf(lo);
}
__device__ __forceinline__ float blo(unsigned u){ return __uint_as_float(u << 16); }
__device__ __forceinline__ float bhi(unsigned u){ return __uint_as_float(u & 0xffff0000u); }
__device__ __forceinline__ short8 cvt8(f4 a, f4 b){
  short8 r;
  #pragma unroll
  for (int j = 0; j < 4; ++j){ r[j] = (short)f2bf(a[j]); r[j+4] = (short)f2bf(b[j]); }
  return r;
}

// ---------------- fallback sentinel ----------------
__global__ void k_sentinel(float* __restrict__ out, int n){
  int i = blockIdx.x * blockDim.x + threadIdx.x;
  if (i < n) out[i] = 12345.0f;
}

// ---------------- x fp32 -> bf16x2 ----------------
__global__ void k_cvt(const float* __restrict__ x, unsigned* __restrict__ xb){
  int i = blockIdx.x * blockDim.x + threadIdx.x;   // i < NN*16
  if (i >= NN * 16) return;
  f4 a = ((const f4*)x)[2 * i];
  f4 b = ((const f4*)x)[2 * i + 1];
  u4 o;
  o[0] = pack2(a[0], a[1]); o[1] = pack2(a[2], a[3]);
  o[2] = pack2(b[0], b[1]); o[3] = pack2(b[2], b[3]);
  ((u4*)xb)[i] = o;
}

// ---------------- histogram (rowgroup-major buckets) ----------------
__global__ void k_hist(const int* __restrict__ src, const int* __restrict__ dst,
                       int* __restrict__ cnt){
  int i = blockIdx.x * blockDim.x + threadIdx.x;
  if (i < NE){
    int s = src[i], d = dst[i];
    atomicAdd(&cnt[(d >> 3) * 104 + (s >> SH) * 8 + (d & 7)], 1);
  }
}

__global__ void k_deg(const int* __restrict__ cnt, int* __restrict__ deg){
  int i = blockIdx.x * blockDim.x + threadIdx.x;
  if (i < NN){
    int g = i >> 3, r = i & 7;
    int s = 0;
    #pragma unroll
    for (int tt = 0; tt < NT; ++tt) s += cnt[g * 104 + tt * 8 + r];
    deg[i] = s;
  }
}

__global__ void k_bsum(const int* __restrict__ cnt, int* __restrict__ bsum, int len){
  __shared__ int sh[256];
  int t = threadIdx.x, b = blockIdx.x;
  int base = b * 1024 + t * 4;
  int s = 0;
  #pragma unroll
  for (int j = 0; j < 4; ++j){ int i = base + j; if (i < len) s += cnt[i]; }
  sh[t] = s; __syncthreads();
  for (int off = 128; off > 0; off >>= 1){
    if (t < off) sh[t] += sh[t + off];
    __syncthreads();
  }
  if (t == 0) bsum[b] = sh[0];
}

__global__ void k_scanp(const int* __restrict__ bsum, int* __restrict__ boff, int nb){
  __shared__ int sh[256];
  int t = threadIdx.x;
  int chunk = (nb + 255) / 256;
  int s = 0;
  for (int j = 0; j < chunk; ++j){ int i = t * chunk + j; if (i < nb) s += bsum[i]; }
  sh[t] = s; __syncthreads();
  int tin = s;
  for (int off = 1; off < 256; off <<= 1){
    int u = (t >= off) ? sh[t - off] : 0;
    __syncthreads();
    sh[t] += u;
    __syncthreads();
  }
  int run = sh[t] - tin;
  for (int j = 0; j < chunk; ++j){
    int i = t * chunk + j;
    if (i < nb){ boff[i] = run; run += bsum[i]; }
  }
}

__global__ void k_scanf(const int* __restrict__ cnt, const int* __restrict__ boff,
                        int* __restrict__ rp, int* __restrict__ pos, int len){
  __shared__ int sh[256];
  int t = threadIdx.x, b = blockIdx.x;
  int base = b * 1024 + t * 4;
  int c[4]; int s = 0;
  #pragma unroll
  for (int j = 0; j < 4; ++j){ int i = base + j; c[j] = (i < len) ? cnt[i] : 0; s += c[j]; }
  sh[t] = s; __syncthreads();
  int tin = s;
  for (int off = 1; off < 256; off <<= 1){
    int u = (t >= off) ? sh[t - off] : 0;
    __syncthreads();
    sh[t] += u;
    __syncthreads();
  }
  int run = boff[b] + sh[t] - tin;
  #pragma unroll
  for (int j = 0; j < 4; ++j){
    int i = base + j;
    if (i < len){
      rp[i] = run; pos[i] = run; run += c[j];
      if (i == len - 1) rp[len] = run;
    }
  }
}

// ---------------- direct dst-windowed scatter to ss16 -------------------------
// PW sequential passes; pass p writes only rowgroups [p*GW,(p+1)*GW) ->
// contiguous ~0.4 MB ss16 + 0.65 MB pos2 window stays L2-resident (kills the
// 17x write amplification seen in r9's k_scatter / r13's k_binB). Edge list
// (12.8 MB) is L3-resident after pass 0, so re-reads are cheap.
__global__ __launch_bounds__(256)
void k_scat(const int* __restrict__ src, const int* __restrict__ dst,
            int* __restrict__ pos, unsigned short* __restrict__ ss16){
  int tid = blockIdx.x * 256 + threadIdx.x;
  int stride = gridDim.x * 256;
  for (int p = 0; p < PW; ++p){
    int glo = p * GW, ghi = glo + GW;
    for (int i = tid; i < NE; i += stride){
      int d = dst[i];
      int g = d >> 3;
      if (g >= glo && g < ghi){
        int s = src[i];
        int b = g * 104 + ((s >> SH) << 3) + (d & 7);
        int q = atomicAdd(&pos[b], 1);
        ss16[q] = (unsigned short)((s & 8191) | ((d & 7) << 13));
      }
    }
  }
}

// ---------------- W packing ----------------
template<int NB16>
__global__ void k_pack(const float* __restrict__ Wl,
                       const float* __restrict__ Wr,
                       unsigned short* __restrict__ Bp){
  constexpr int DOUT = NB16 * 16;
  int idx = blockIdx.x * blockDim.x + threadIdx.x;
  if (idx >= 8 * NB16 * 64) return;
  int lane = idx & 63;
  int nb = (idx >> 6) % NB16;
  int ks = idx / (64 * NB16);
  int n = nb * 16 + (lane & 15);
  int k0 = ks * 32 + (lane >> 4) * 8;
  short8 v;
  #pragma unroll
  for (int j = 0; j < 8; ++j){
    int k = k0 + j;
    float w = (k < 128) ? Wl[k * DOUT + n] : Wr[(k - 128) * DOUT + n];
    v[j] = (short)f2bf(w);
  }
  ((short8*)Bp)[idx] = v;
}

// ---------------- fused tiled mean-aggregate + dual-GEMM (+BN+ReLU) ----------
// Rowgroup-major ss16: the wave's 128-edge worklist is ONE contiguous range,
// ordered (tile,row). Tags loaded 8-at-a-time via aligned u4 (scalar path);
// tile tracked by rare wave-uniform advances over prefetched bounds.
template<int NB16, bool DO_BN>
__global__ __launch_bounds__(256)
void k_fused(const unsigned* __restrict__ Xb,
             const int* __restrict__ rp2, const unsigned short* __restrict__ ss16,
             const int* __restrict__ deg,
             const unsigned short* __restrict__ Bp,
             const float* __restrict__ bias,
             const float* __restrict__ bg, const float* __restrict__ bb,
             const float* __restrict__ bm, const float* __restrict__ bv,
             unsigned short* __restrict__ OutB, float* __restrict__ OutF){
  constexpr int DOUT = NB16 * 16;
  constexpr int NBW = NB16 / 4;
  __shared__ float smF[32][FST];
  const int t = threadIdx.x;
  const int lane = t & 63;
  const int wv = t >> 6;
  const int m0 = blockIdx.x * 32;
  const int row0 = m0 + wv * 8;
  const int g = row0 >> 3;

  for (int i = t; i < 32 * FST; i += 256) (&smF[0][0])[i] = 0.f;
  __syncthreads();

  float* const base = &smF[wv * 8][0];

  // bounds: rp2[g*104 + k*8], k=0..13 (k=13 -> next rowgroup start = range end)
  int bAll = (lane < 14) ? rp2[g * 104 + lane * 8] : 0;

  int tt = 0;
  int e        = __builtin_amdgcn_readfirstlane(__shfl(bAll, 0));
  const int end= __builtin_amdgcn_readfirstlane(__shfl(bAll, 13));
  int nb       = __builtin_amdgcn_readfirstlane(__shfl(bAll, 1));

  float cx = 0.f, cy = 0.f;
  int cur = 0;

  #define ADV(ee) { while ((ee) >= nb){ ++tt; nb = __builtin_amdgcn_readfirstlane(__shfl(bAll, tt + 1)); } }
  #define ONE(tg) { \
    int _row = (tg) >> 13; \
    unsigned _u = Xb[(size_t)(((unsigned)tt << SH) | ((unsigned)(tg) & 8191u)) * 64 + lane]; \
    if (_row != cur){ float* _p = base + cur * FST + 2 * lane; _p[0] += cx; _p[1] += cy; cx = 0.f; cy = 0.f; cur = _row; } \
    cx += blo(_u); cy += bhi(_u); }

  // head peel to 16B alignment (once per wave)
  while (e < end && (e & 7)){
    ADV(e);
    int tg = __builtin_amdgcn_readfirstlane((int)ss16[e]);
    ONE(tg);
    ++e;
  }
  // body: 8 tags per aligned 16B load; compute -> gather -> consume
  while (e + 8 <= end){
    u4 q = *(const u4*)(ss16 + e);
    unsigned d0 = __builtin_amdgcn_readfirstlane(q[0]);
    unsigned d1 = __builtin_amdgcn_readfirstlane(q[1]);
    unsigned d2 = __builtin_amdgcn_readfirstlane(q[2]);
    unsigned d3 = __builtin_amdgcn_readfirstlane(q[3]);
    int tg[8] = { (int)(d0 & 0xffffu), (int)(d0 >> 16), (int)(d1 & 0xffffu), (int)(d1 >> 16),
                  (int)(d2 & 0xffffu), (int)(d2 >> 16), (int)(d3 & 0xffffu), (int)(d3 >> 16) };
    unsigned sidx[8]; int row[8];
    #pragma unroll
    for (int i = 0; i < 8; ++i){
      ADV(e + i);
      sidx[i] = ((unsigned)tt << SH) | ((unsigned)tg[i] & 8191u);
      row[i] = tg[i] >> 13;
    }
    unsigned u[8];
    #pragma unroll
    for (int i = 0; i < 8; ++i) u[i] = Xb[(size_t)sidx[i] * 64 + lane];
    #pragma unroll
    for (int i = 0; i < 8; ++i){
      if (row[i] != cur){ float* _p = base + cur * FST + 2 * lane; _p[0] += cx; _p[1] += cy; cx = 0.f; cy = 0.f; cur = row[i]; }
      cx += blo(u[i]); cy += bhi(u[i]);
    }
    e += 8;
  }
  // tail peel
  while (e < end){
    ADV(e);
    int tg = __builtin_amdgcn_readfirstlane((int)ss16[e]);
    ONE(tg);
    ++e;
  }
  { float* p = base + cur * FST + 2 * lane; p[0] += cx; p[1] += cy; }
  #undef ONE
  #undef ADV
  __syncthreads();

  // normalize
  {
    int row = t >> 3;
    int d = deg[m0 + row];
    float inv = (d > 0) ? 1.f / (float)d : 0.f;
    float* pr = &smF[row][(t & 7) * 16];
    #pragma unroll
    for (int i = 0; i < 16; ++i) pr[i] *= inv;
  }
  __syncthreads();

  // ---- phase 2: dual GEMM ----
  const int q2 = lane >> 4, lr = lane & 15;
  const short8* pb = (const short8*)Bp + lane;
  f4 acc[2][NBW];
  #pragma unroll
  for (int gg = 0; gg < 2; ++gg)
    #pragma unroll
    for (int j = 0; j < NBW; ++j)
      acc[gg][j] = (f4){0.f, 0.f, 0.f, 0.f};

  #pragma unroll
  for (int ks = 0; ks < 4; ++ks){
    const float* r0 = &smF[lr][ks * 32 + q2 * 8];
    const float* r1 = &smF[lr + 16][ks * 32 + q2 * 8];
    short8 a0 = cvt8(*(const f4*)r0, *(const f4*)(r0 + 4));
    short8 a1 = cvt8(*(const f4*)r1, *(const f4*)(r1 + 4));
    #pragma unroll
    for (int j = 0; j < NBW; ++j){
      int nb2 = wv * NBW + j;
      short8 b = pb[(ks * NB16 + nb2) * 64];
      acc[0][j] = __builtin_amdgcn_mfma_f32_16x16x32_bf16(a0, b, acc[0][j], 0, 0, 0);
      acc[1][j] = __builtin_amdgcn_mfma_f32_16x16x32_bf16(a1, b, acc[1][j], 0, 0, 0);
    }
  }
  #pragma unroll
  for (int ks = 0; ks < 4; ++ks){
    short8 a0 = *(const short8*)(Xb + (size_t)(m0 + lr) * 64 + q2*4 + ks*16);
    short8 a1 = *(const short8*)(Xb + (size_t)(m0 + lr + 16) * 64 + q2*4 + ks*16);
    #pragma unroll
    for (int j = 0; j < NBW; ++j){
      int nb2 = wv * NBW + j;
      short8 b = pb[((4 + ks) * NB16 + nb2) * 64];
      acc[0][j] = __builtin_amdgcn_mfma_f32_16x16x32_bf16(a0, b, acc[0][j], 0, 0, 0);
      acc[1][j] = __builtin_amdgcn_mfma_f32_16x16x32_bf16(a1, b, acc[1][j], 0, 0, 0);
    }
  }

  // ---- epilogue ----
  #pragma unroll
  for (int j = 0; j < NBW; ++j){
    int col = (wv * NBW + j) * 16 + lr;
    float S = 1.f, T;
    if constexpr (DO_BN){
      float s = bg[col] * rsqrtf(bv[col] + 1e-5f);
      S = s;
      T = (bias[col] - bm[col]) * s + bb[col];
    } else {
      T = bias[col];
    }
    #pragma unroll
    for (int r = 0; r < 4; ++r){
      int row = m0 + q2 * 4 + r;
      float y0 = acc[0][j][r] * S + T;
      float y1 = acc[1][j][r] * S + T;
      if constexpr (DO_BN){
        y0 = y0 > 0.f ? y0 : 0.f;
        y1 = y1 > 0.f ? y1 : 0.f;
        OutB[(size_t)row * DOUT + col] = f2bf(y0);
        OutB[(size_t)(row + 16) * DOUT + col] = f2bf(y1);
      } else {
        OutF[(size_t)row * DOUT + col] = y0;
        OutF[(size_t)(row + 16) * DOUT + col] = y1;
      }
    }
  }
}

extern "C" void kernel_launch(void* const* d_in, const int* in_sizes, int n_in,
                              void* d_out, int out_size, void* d_ws, size_t ws_size,
                              hipStream_t stream){
  const float* x = (const float*)d_in[0];
  const int* ei = (const int*)d_in[1];
  const float* Wl0 = (const float*)d_in[2];
  const float* Wr0 = (const float*)d_in[3];
  const float* bl0 = (const float*)d_in[4];
  const float* Wl1 = (const float*)d_in[5];
  const float* Wr1 = (const float*)d_in[6];
  const float* bl1 = (const float*)d_in[7];
  const float* Wl2 = (const float*)d_in[8];
  const float* Wr2 = (const float*)d_in[9];
  const float* bl2 = (const float*)d_in[10];
  const float* g0 = (const float*)d_in[11];
  const float* b0 = (const float*)d_in[12];
  const float* bm0 = (const float*)d_in[13];
  const float* bv0 = (const float*)d_in[14];
  const float* g1 = (const float*)d_in[15];
  const float* b1 = (const float*)d_in[16];
  const float* bm1 = (const float*)d_in[17];
  const float* bv1 = (const float*)d_in[18];

  const size_t REQUIRED = 51600000;
  if (ws_size < REQUIRED){
    k_sentinel<<<(out_size + 255) / 256, 256, 0, stream>>>((float*)d_out, out_size);
    return;
  }

  char* w = (char*)d_ws;
  size_t off = 0;
  auto alloc = [&](size_t bytes) -> char* {
    char* p = w + off; off = (off + bytes + 255) & ~(size_t)255; return p;
  };
  int* rp2 = (int*)alloc((size_t)(LEN + 1) * 4);
  unsigned short* ss16 = (unsigned short*)alloc((size_t)NE * 2);
  unsigned short* bp0 = (unsigned short*)alloc(8 * 8 * 64 * 8 * 2);
  unsigned short* bp1 = (unsigned short*)alloc(8 * 8 * 64 * 8 * 2);
  unsigned short* bp2 = (unsigned short*)alloc(8 * 4 * 64 * 8 * 2);
  unsigned* xb = (unsigned*)alloc((size_t)NN * 64 * 4);   // bf16x2 x; reused as h2
  unsigned short* h2 = (unsigned short*)xb;
  int* cnt2 = (int*)alloc((size_t)LEN * 4);
  int* pos2 = (int*)alloc((size_t)LEN * 4);
  int* deg  = (int*)alloc((size_t)NN * 4);
  int* bsum = (int*)alloc(NB_SCAN * 4);
  int* boff = (int*)alloc(NB_SCAN * 4);
  unsigned short* h1 = (unsigned short*)d_out;            // 25.6 MB, exactly d_out

  const int* srcI = ei;
  const int* dstI = ei + NE;

  hipMemsetAsync(cnt2, 0, (size_t)LEN * 4, stream);
  k_cvt<<<(NN * 16 + 255) / 256, 256, 0, stream>>>(x, xb);
  k_hist<<<(NE + 255) / 256, 256, 0, stream>>>(srcI, dstI, cnt2);
  k_deg<<<(NN + 255) / 256, 256, 0, stream>>>(cnt2, deg);
  k_bsum<<<NB_SCAN, 256, 0, stream>>>(cnt2, bsum, LEN);
  k_scanp<<<1, 256, 0, stream>>>(bsum, boff, NB_SCAN);
  k_scanf<<<NB_SCAN, 256, 0, stream>>>(cnt2, boff, rp2, pos2, LEN);
  k_scat<<<1024, 256, 0, stream>>>(srcI, dstI, pos2, ss16);
  k_pack<8><<<16, 256, 0, stream>>>(Wl0, Wr0, bp0);
  k_pack<8><<<16, 256, 0, stream>>>(Wl1, Wr1, bp1);
  k_pack<4><<<8, 256, 0, stream>>>(Wl2, Wr2, bp2);

  k_fused<8, true ><<<3125, 256, 0, stream>>>(xb, rp2, ss16, deg, bp0,
      bl0, g0, b0, bm0, bv0, h1, nullptr);
  k_fused<8, true ><<<3125, 256, 0, stream>>>((const unsigned*)h1, rp2, ss16, deg, bp1,
      bl1, g1, b1, bm1, bv1, h2, nullptr);
  k_fused<4, false><<<3125, 256, 0, stream>>>((const unsigned*)h2, rp2, ss16, deg, bp2,
      bl2, nullptr, nullptr, nullptr, nullptr, nullptr, (float*)d_out);
}